// Round 1
// baseline (957.439 us; speedup 1.0000x reference)
//
#include <hip/hip_runtime.h>

// FastRadonTransform: x (B,C,H,W) f32, angles (B,K) f32 -> sinogram (B,C,H,K) f32
// out[b,c,h,k] = sum_w bilinear_sample(x[b,c], rot_theta(h,w)), zero-padded,
// align_corners=True. Per w-step the sample point moves by exactly
// (cos, -sin) pixels, so coords are incremental FMAs; trig once per thread.

constexpr int B = 2, C = 3, H = 384, W = 384, K = 180;

__global__ __launch_bounds__(64) void radon_fwd(
    const float* __restrict__ x,       // (B,C,H,W)
    const float* __restrict__ angles,  // (B,K)
    float* __restrict__ out)           // (B,C,H,K)
{
    const int g = blockIdx.x * 64 + threadIdx.x;   // [0, B*K*H); wave-uniform (b,k)
    const int h = g % H;
    const int t = g / H;
    const int k = t % K;
    const int b = t / K;

    const float theta = angles[b * K + k] * (3.14159265358979323846f / 180.0f);
    float sth, cth;
    sincosf(theta, &sth, &cth);

    // yy in [-1,1]; fx = 0.5*(W-1)*(xx*c + yy*s + 1); fy = 0.5*(H-1)*(-xx*s + yy*c + 1)
    const float yy  = fmaf(2.0f / (H - 1), (float)h, -1.0f);
    const float fx0 = 0.5f * (W - 1) * (fmaf(yy, sth, -cth) + 1.0f);
    const float fy0 = 0.5f * (H - 1) * (fmaf(yy, cth,  sth) + 1.0f);
    const float dfx = cth;   // exact per-w pixel step (H==W)
    const float dfy = -sth;

    const float* __restrict__ p0 = x + (size_t)b * C * H * W;
    const float* __restrict__ p1 = p0 + H * W;
    const float* __restrict__ p2 = p1 + H * W;

    float acc0 = 0.f, acc1 = 0.f, acc2 = 0.f;

    #pragma unroll 4
    for (int w = 0; w < W; ++w) {
        const float fw  = (float)w;
        const float fx  = fmaf(fw, dfx, fx0);
        const float fy  = fmaf(fw, dfy, fy0);
        const float xf  = floorf(fx);
        const float yf  = floorf(fy);
        const float wx1 = fx - xf;
        const float wy1 = fy - yf;
        const float wx0 = 1.0f - wx1;
        const float wy0 = 1.0f - wy1;
        const int ix = (int)xf;
        const int iy = (int)yf;

        // zero-padding: fold validity into weights, clamp indices for safe loads
        const float vx0 = ((unsigned)ix       < (unsigned)W) ? 1.0f : 0.0f;
        const float vx1 = ((unsigned)(ix + 1) < (unsigned)W) ? 1.0f : 0.0f;
        const float vy0 = ((unsigned)iy       < (unsigned)H) ? 1.0f : 0.0f;
        const float vy1 = ((unsigned)(iy + 1) < (unsigned)H) ? 1.0f : 0.0f;
        const float ax0 = wx0 * vx0;
        const float ax1 = wx1 * vx1;
        const float ay0 = wy0 * vy0;
        const float ay1 = wy1 * vy1;

        const int xc0 = min(max(ix, 0), W - 1);
        const int xc1 = min(max(ix + 1, 0), W - 1);
        const int yc0 = min(max(iy, 0), H - 1);
        const int yc1 = min(max(iy + 1, 0), H - 1);
        const int o00 = yc0 * W + xc0;
        const int o01 = yc0 * W + xc1;
        const int o10 = yc1 * W + xc0;
        const int o11 = yc1 * W + xc1;

        {
            const float v00 = p0[o00], v01 = p0[o01], v10 = p0[o10], v11 = p0[o11];
            acc0 = fmaf(ay0, fmaf(ax0, v00, ax1 * v01),
                   fmaf(ay1, fmaf(ax0, v10, ax1 * v11), acc0));
        }
        {
            const float v00 = p1[o00], v01 = p1[o01], v10 = p1[o10], v11 = p1[o11];
            acc1 = fmaf(ay0, fmaf(ax0, v00, ax1 * v01),
                   fmaf(ay1, fmaf(ax0, v10, ax1 * v11), acc1));
        }
        {
            const float v00 = p2[o00], v01 = p2[o01], v10 = p2[o10], v11 = p2[o11];
            acc2 = fmaf(ay0, fmaf(ax0, v00, ax1 * v01),
                   fmaf(ay1, fmaf(ax0, v10, ax1 * v11), acc2));
        }
    }

    // out[((b*C + c)*H + h)*K + k]
    float* op = out + ((size_t)(b * C) * H + h) * K + k;
    op[0]                  = acc0;
    op[(size_t)H * K]      = acc1;
    op[2 * (size_t)H * K]  = acc2;
}

extern "C" void kernel_launch(void* const* d_in, const int* in_sizes, int n_in,
                              void* d_out, int out_size, void* d_ws, size_t ws_size,
                              hipStream_t stream) {
    const float* x      = (const float*)d_in[0];
    const float* angles = (const float*)d_in[1];
    float* out          = (float*)d_out;

    const int total = B * K * H;          // 138240 threads, 2160 one-wave blocks
    radon_fwd<<<total / 64, 64, 0, stream>>>(x, angles, out);
}

// Round 3
// 294.925 us; speedup vs baseline: 3.2464x; 3.2464x over previous
//
#include <hip/hip_runtime.h>
#include <math.h>

// FastRadonTransform via LDS-staged rotated-tile sampling.
// Sample grid: fx = A + w*cos + h*sin ; fy = Bc - w*sin + h*cos  (exact, H==W,
// align_corners=True). A 32x32 (h,w) sample tile is a rigid rotated 32x32 px
// patch -> bbox <= 47x47. Stage bbox (zero-filled outside image -> zero-padding
// for free) into LDS, bilinear-read from LDS (odd stride 49 -> conflict-free),
// reduce over w with shuffles. One block per (b,k,h-tile); loops 12 w-tiles.

constexpr int B = 2, C = 3, H = 384, W = 384, K = 180;
constexpr int TILE = 32;
constexpr int NTW  = W / TILE;   // 12
constexpr int NTH  = H / TILE;   // 12
constexpr int BB   = 48;         // bbox edge (needed <= 47)
constexpr int BBS  = 49;         // padded LDS row stride (odd -> no bank conflicts)

__global__ __launch_bounds__(256) void radon_tile(
    const float* __restrict__ x,       // (B,C,H,W)
    const float* __restrict__ angles,  // (B,K)
    float* __restrict__ out)           // (B,C,H,K)
{
    __shared__ float lds[C][BB * BBS];          // 3 * 48 * 49 * 4B = 27.6 KiB

    const int bid = blockIdx.x;
    const int th  = bid % NTH;                  // h-tile index
    const int bk  = bid / NTH;
    const int k   = bk % K;
    const int b   = bk / K;

    const int tid = threadIdx.x;
    const int ww  = tid & 31;                   // w within tile
    const int hh  = tid >> 5;                   // 0..7; h = h0 + hh + 8*i

    const float theta = angles[b * K + k] * (3.14159265358979323846f / 180.0f);
    float sth, cth;
    sincosf(theta, &sth, &cth);

    const float A  = 0.5f * (W - 1) * (1.0f - cth - sth);
    const float Bc = 0.5f * (H - 1) * (1.0f + sth - cth);

    const int h0 = th * TILE;
    const float hbase = (float)(h0 + hh);
    const float s8 = 8.0f * sth, c8 = 8.0f * cth;

    const float* __restrict__ img = x + (size_t)b * C * H * W;

    float acc[4][C];
    #pragma unroll
    for (int i = 0; i < 4; ++i)
        #pragma unroll
        for (int c = 0; c < C; ++c) acc[i][c] = 0.0f;

    for (int tw = 0; tw < NTW; ++tw) {
        const int w0 = tw * TILE;

        // bbox of the tile's sample points from the 4 corners (linear map)
        const float w0f = (float)w0, w1f = (float)(w0 + TILE - 1);
        const float h0f = (float)h0, h1f = (float)(h0 + TILE - 1);
        const float fxa = A + w0f * cth + h0f * sth;
        const float fxb = A + w1f * cth + h0f * sth;
        const float fxc = A + w0f * cth + h1f * sth;
        const float fxd = A + w1f * cth + h1f * sth;
        const float fya = Bc - w0f * sth + h0f * cth;
        const float fyb = Bc - w1f * sth + h0f * cth;
        const float fyc = Bc - w0f * sth + h1f * cth;
        const float fyd = Bc - w1f * sth + h1f * cth;
        const int x_min = (int)floorf(fminf(fminf(fxa, fxb), fminf(fxc, fxd))) - 1;
        const int y_min = (int)floorf(fminf(fminf(fya, fyb), fminf(fyc, fyd))) - 1;

        // stage bbox into LDS, zero outside image (padding_mode='zeros')
        #pragma unroll
        for (int c = 0; c < C; ++c) {
            const float* __restrict__ plane = img + (size_t)c * H * W;
            #pragma unroll
            for (int j = 0; j < 9; ++j) {              // 48*48 / 256 = 9
                const int e  = tid + j * 256;
                const int r  = e / BB;
                const int cc = e - r * BB;
                const int gy = y_min + r;
                const int gx = x_min + cc;
                const bool valid = ((unsigned)gy < (unsigned)H) &
                                   ((unsigned)gx < (unsigned)W);
                const int gyc = min(max(gy, 0), H - 1);
                const int gxc = min(max(gx, 0), W - 1);
                const float v = plane[gyc * W + gxc];
                lds[c][r * BBS + cc] = valid ? v : 0.0f;
            }
        }
        __syncthreads();

        // 4 samples per thread: (h0+hh+8i, w0+ww)
        const float wf = (float)(w0 + ww);
        float fx = fmaf(hbase, sth, fmaf(wf,  cth, A));
        float fy = fmaf(hbase, cth, fmaf(wf, -sth, Bc));

        #pragma unroll
        for (int i = 0; i < 4; ++i) {
            const float xf = floorf(fx), yf = floorf(fy);
            const int lx = (int)xf - x_min;
            const int ly = (int)yf - y_min;
            const float wx1 = fx - xf, wy1 = fy - yf;
            const float wx0 = 1.0f - wx1, wy0 = 1.0f - wy1;
            const float w00 = wy0 * wx0, w01 = wy0 * wx1;
            const float w10 = wy1 * wx0, w11 = wy1 * wx1;
            const int idx = ly * BBS + lx;
            #pragma unroll
            for (int c = 0; c < C; ++c) {
                const float p00 = lds[c][idx];
                const float p01 = lds[c][idx + 1];
                const float p10 = lds[c][idx + BBS];
                const float p11 = lds[c][idx + BBS + 1];
                acc[i][c] = fmaf(w00, p00, fmaf(w01, p01,
                            fmaf(w10, p10, fmaf(w11, p11, acc[i][c]))));
            }
            fx += s8;
            fy += c8;
        }
        __syncthreads();
    }

    // reduce over the 32 ww-lanes (xor masks <32 stay within the 32-group)
    #pragma unroll
    for (int i = 0; i < 4; ++i) {
        #pragma unroll
        for (int c = 0; c < C; ++c) {
            float s = acc[i][c];
            #pragma unroll
            for (int m = 16; m >= 1; m >>= 1) s += __shfl_xor(s, m, 64);
            if (ww == 0) {
                const int h = h0 + hh + 8 * i;
                out[((size_t)(b * C + c) * H + h) * K + k] = s;
            }
        }
    }
}

extern "C" void kernel_launch(void* const* d_in, const int* in_sizes, int n_in,
                              void* d_out, int out_size, void* d_ws, size_t ws_size,
                              hipStream_t stream) {
    const float* x      = (const float*)d_in[0];
    const float* angles = (const float*)d_in[1];
    float* out          = (float*)d_out;

    radon_tile<<<B * K * NTH, 256, 0, stream>>>(x, angles, out);  // 4320 blocks
}

// Round 4
// 275.992 us; speedup vs baseline: 3.4691x; 1.0686x over previous
//
#include <hip/hip_runtime.h>
#include <math.h>

// FastRadonTransform via LDS-staged rotated-tile sampling, v2.
// fx = A + w*cos + h*sin ; fy = Bc - w*sin + h*cos (exact, H==W, align_corners).
// 32x32 (h,w) sample tile -> rigid rotated patch, bbox <= 46x47 px.
// Stage a float4-aligned 48(rows)x64(cols) window into LDS (stride 65, odd ->
// conflict-free bilinear reads). Division-free staging map: s=tid+256j,
// r=s>>4, col4=s&15 -> 9 aligned dwordx4 loads/thread. Next tile's loads are
// issued before sampling the current tile (latency hiding). Tiles with
// bbox entirely off-image are skipped (zero contribution).

constexpr int B = 2, C = 3, H = 384, W = 384, K = 180;
constexpr int TILE = 32;
constexpr int NTW  = W / TILE;      // 12
constexpr int NTH  = H / TILE;      // 12
constexpr int ROWS = 48;            // staged rows
constexpr int COLS = 64;            // staged cols (sampling touches < 52)
constexpr int BBS  = 65;            // LDS row stride (odd -> conflict-free)
constexpr int CHS  = ROWS * BBS;    // 3120 floats per channel

struct Cat { int stage; int xal; int ym; };

__device__ __forceinline__ Cat tile_cat(float A, float Bc, float sth, float cth,
                                        int h0, int tw) {
    const float w0f = (float)(tw * TILE), w1f = w0f + (TILE - 1);
    const float h0f = (float)h0,          h1f = h0f + (TILE - 1);
    const float minfx = A  + fminf(w0f * cth, w1f * cth) + fminf(h0f * sth, h1f * sth);
    const float minfy = Bc + fminf(-w0f * sth, -w1f * sth) + fminf(h0f * cth, h1f * cth);
    Cat c;
    const int xm = (int)floorf(minfx) - 1;
    c.ym  = (int)floorf(minfy) - 1;
    c.xal = xm & ~3;
    const bool skip = (xm + 47 < 0) | (xm > W - 1) | (c.ym + 47 < 0) | (c.ym > H - 1);
    c.stage = skip ? 0 : 1;
    return c;
}

// Issue 9 aligned float4 loads (clamped addresses -> always safe).
__device__ __forceinline__ void issue_loads(const float* __restrict__ img,
                                            int tid, int xal, int ym,
                                            float4 (&pf)[3][3]) {
    #pragma unroll
    for (int c = 0; c < C; ++c) {
        const float* __restrict__ plane = img + c * (H * W);
        #pragma unroll
        for (int j = 0; j < 3; ++j) {
            const int s  = tid + 256 * j;          // < 768
            const int r  = s >> 4;                 // 0..47
            const int c4 = (s & 15) * 4;           // 0..60
            const int gy = min(max(ym + r, 0), H - 1);
            const int gx = min(max(xal + c4, 0), W - 4);   // stays 4-aligned
            pf[c][j] = *reinterpret_cast<const float4*>(plane + gy * W + gx);
        }
    }
}

// Write staged regs to LDS; boundary groups re-fetch per-component with
// zero-padding semantics (rare: only bbox-crossing lanes diverge).
__device__ __forceinline__ void write_stage(const float* __restrict__ img,
                                            float* __restrict__ sm,
                                            int tid, int xal, int ym,
                                            const float4 (&pf)[3][3]) {
    #pragma unroll
    for (int c = 0; c < C; ++c) {
        const float* __restrict__ plane = img + c * (H * W);
        #pragma unroll
        for (int j = 0; j < 3; ++j) {
            const int s  = tid + 256 * j;
            const int r  = s >> 4;
            const int c4 = (s & 15) * 4;
            const int gy = ym + r;
            const int gx = xal + c4;
            float* dst = sm + c * CHS + r * BBS + c4;
            const bool rowok = ((unsigned)gy < (unsigned)H);
            const float4 v = pf[c][j];
            if (rowok && gx >= 0 && gx <= W - 4) {
                dst[0] = v.x; dst[1] = v.y; dst[2] = v.z; dst[3] = v.w;
            } else {
                const int gyc = min(max(gy, 0), H - 1);
                #pragma unroll
                for (int u = 0; u < 4; ++u) {
                    const int gxu = gx + u;
                    const bool ok = rowok && ((unsigned)gxu < (unsigned)W);
                    const int gxc = min(max(gxu, 0), W - 1);
                    const float t = plane[gyc * W + gxc];
                    dst[u] = ok ? t : 0.0f;
                }
            }
        }
    }
}

__global__ __launch_bounds__(256) void radon_tile(
    const float* __restrict__ x,       // (B,C,H,W)
    const float* __restrict__ angles,  // (B,K)
    float* __restrict__ out)           // (B,C,H,K)
{
    __shared__ float sm[C * CHS];      // 3*3120*4 = 37440 B

    const int bid = blockIdx.x;
    const int th  = bid % NTH;
    const int bk  = bid / NTH;
    const int k   = bk % K;
    const int b   = bk / K;

    const int tid = threadIdx.x;
    const int ww  = tid & 31;          // w within tile
    const int hh  = tid >> 5;          // 0..7; h = h0 + hh + 8*i

    const float theta = angles[b * K + k] * (3.14159265358979323846f / 180.0f);
    float sth, cth;
    sincosf(theta, &sth, &cth);

    const float A  = 0.5f * (W - 1) * (1.0f - cth - sth);
    const float Bc = 0.5f * (H - 1) * (1.0f + sth - cth);

    const int h0 = th * TILE;
    const float hbase = (float)(h0 + hh);
    const float s8 = 8.0f * sth, c8 = 8.0f * cth;

    const float* __restrict__ img = x + (size_t)b * (C * H * W);

    float acc[4][C];
    #pragma unroll
    for (int i = 0; i < 4; ++i)
        #pragma unroll
        for (int c = 0; c < C; ++c) acc[i][c] = 0.0f;

    float4 pf[3][3];
    Cat cur = tile_cat(A, Bc, sth, cth, h0, 0);
    if (cur.stage) issue_loads(img, tid, cur.xal, cur.ym, pf);

    for (int tw = 0; tw < NTW; ++tw) {
        Cat nxt; nxt.stage = 0; nxt.xal = 0; nxt.ym = 0;
        if (tw + 1 < NTW) nxt = tile_cat(A, Bc, sth, cth, h0, tw + 1);

        if (cur.stage) {
            __syncthreads();                       // prior sampling done
            write_stage(img, sm, tid, cur.xal, cur.ym, pf);
        }
        if (nxt.stage) issue_loads(img, tid, nxt.xal, nxt.ym, pf);  // overlap w/ sampling
        if (cur.stage) {
            __syncthreads();                       // LDS tile ready
            const float wf = (float)(tw * TILE + ww);
            float fx = fmaf(hbase, sth, fmaf(wf,  cth, A));
            float fy = fmaf(hbase, cth, fmaf(wf, -sth, Bc));
            #pragma unroll
            for (int i = 0; i < 4; ++i) {
                const float xf = floorf(fx), yf = floorf(fy);
                const int lx = (int)xf - cur.xal;  // in [1, 49]
                const int ly = (int)yf - cur.ym;   // in [1, 46]
                const float wx1 = fx - xf, wy1 = fy - yf;
                const float wx0 = 1.0f - wx1, wy0 = 1.0f - wy1;
                const float w00 = wy0 * wx0, w01 = wy0 * wx1;
                const float w10 = wy1 * wx0, w11 = wy1 * wx1;
                const int idx = ly * BBS + lx;
                #pragma unroll
                for (int c = 0; c < C; ++c) {
                    const float p00 = sm[c * CHS + idx];
                    const float p01 = sm[c * CHS + idx + 1];
                    const float p10 = sm[c * CHS + idx + BBS];
                    const float p11 = sm[c * CHS + idx + BBS + 1];
                    acc[i][c] = fmaf(w00, p00, fmaf(w01, p01,
                                fmaf(w10, p10, fmaf(w11, p11, acc[i][c]))));
                }
                fx += s8; fy += c8;
            }
        }
        cur = nxt;
    }

    // reduce over the 32 ww-lanes (xor masks <32 stay within the ww group)
    #pragma unroll
    for (int i = 0; i < 4; ++i) {
        #pragma unroll
        for (int c = 0; c < C; ++c) {
            float s = acc[i][c];
            #pragma unroll
            for (int m = 16; m >= 1; m >>= 1) s += __shfl_xor(s, m, 64);
            if (ww == 0) {
                const int h = h0 + hh + 8 * i;
                out[((size_t)(b * C + c) * H + h) * K + k] = s;
            }
        }
    }
}

extern "C" void kernel_launch(void* const* d_in, const int* in_sizes, int n_in,
                              void* d_out, int out_size, void* d_ws, size_t ws_size,
                              hipStream_t stream) {
    const float* x      = (const float*)d_in[0];
    const float* angles = (const float*)d_in[1];
    float* out          = (float*)d_out;

    radon_tile<<<B * K * NTH, 256, 0, stream>>>(x, angles, out);  // 4320 blocks
}

// Round 6
// 237.791 us; speedup vs baseline: 4.0264x; 1.1606x over previous
//
#include <hip/hip_runtime.h>
#include <math.h>

// FastRadonTransform via LDS-staged rotated-tile sampling, v4.
// fx = A + w*cos + h*sin ; fy = Bc - w*sin + h*cos (exact, H==W, align_corners).
// 32x32 (h,w) sample tile -> rigid rotated patch, bbox <= 46x47 px.
// Stage 48(rows)x64(cols) float4-aligned window per channel into LDS.
// Swizzle: slot = r*64 + (col ^ ((r&7)<<2)) — an IN-ROW permutation (BBS=64
// makes it bijective; the v3 BBS=52 variant XOR'd across row boundaries and
// corrupted data). Spreads angle-resonant reads across 8 banks; writes stay
// float4-contiguous. Interior windows stage via pure dwordx4 loads + b128 LDS
// writes; boundary windows take a per-element zero-padded path. Next tile's
// global loads are issued before sampling the current tile (latency hiding).

constexpr int B = 2, C = 3, H = 384, W = 384, K = 180;
constexpr int TILE = 32;
constexpr int NTW  = W / TILE;      // 12
constexpr int NTH  = H / TILE;      // 12
constexpr int ROWS = 48;
constexpr int BBS  = 64;            // row stride (mult of 32 -> bijective swizzle)
constexpr int CHS  = ROWS * BBS;    // 3072 floats = 12288 B per channel

struct Cat { int stage; int xal; int ym; };

__device__ __forceinline__ Cat tile_cat(float A, float Bc, float sth, float cth,
                                        int h0, int tw) {
    const float w0f = (float)(tw * TILE), w1f = w0f + (TILE - 1);
    const float h0f = (float)h0,          h1f = h0f + (TILE - 1);
    const float minfx = A  + fminf(w0f * cth, w1f * cth) + fminf(h0f * sth, h1f * sth);
    const float minfy = Bc + fminf(-w0f * sth, -w1f * sth) + fminf(h0f * cth, h1f * cth);
    Cat c;
    const int xm = (int)floorf(minfx) - 1;
    c.ym  = (int)floorf(minfy) - 1;
    c.xal = xm & ~3;
    const bool skip = (xm + 47 < 0) | (xm > W - 1) | (c.ym + 47 < 0) | (c.ym > H - 1);
    c.stage = skip ? 0 : 1;
    return c;
}

// Staging map: u = tid + 256j (j<3), r = u>>4 in [0,48), g = u&15 in [0,16).
// Window: rows ym..ym+47, cols xal..xal+63 (xal 4-aligned). All lanes active.
__device__ __forceinline__ void issue_loads(const float* __restrict__ img,
                                            int tid, int xal, int ym,
                                            float4 (&pf)[C][3]) {
    #pragma unroll
    for (int c = 0; c < C; ++c) {
        const float* __restrict__ plane = img + c * (H * W);
        #pragma unroll
        for (int j = 0; j < 3; ++j) {
            const int u = tid + 256 * j;
            const int r = u >> 4;
            const int g = u & 15;
            const int gy = min(max(ym + r, 0), H - 1);
            const int gx = min(max(xal + 4 * g, 0), W - 4);  // stays 4-aligned
            pf[c][j] = *reinterpret_cast<const float4*>(plane + gy * W + gx);
        }
    }
}

__device__ __forceinline__ void write_stage(const float* __restrict__ img,
                                            float* __restrict__ sm,
                                            int tid, int xal, int ym,
                                            const float4 (&pf)[C][3]) {
    const bool interior = (ym >= 0) & (ym <= H - ROWS) &
                          (xal >= 0) & (xal <= W - BBS);
    #pragma unroll
    for (int c = 0; c < C; ++c) {
        const float* __restrict__ plane = img + c * (H * W);
        #pragma unroll
        for (int j = 0; j < 3; ++j) {
            const int u = tid + 256 * j;
            const int r = u >> 4;
            const int g = u & 15;
            // in-row swizzle: slot col = (4g) ^ ((r&7)<<2), still 4-aligned
            const int bs = c * CHS + r * BBS + ((4 * g) ^ ((r & 7) << 2));
            const float4 v = pf[c][j];
            if (interior) {
                *reinterpret_cast<float4*>(sm + bs) = v;
            } else {
                const int gy = ym + r;
                const int gx = xal + 4 * g;
                const bool rowok = ((unsigned)gy < (unsigned)H);
                if (rowok && gx >= 0 && gx <= W - 4) {
                    *reinterpret_cast<float4*>(sm + bs) = v;
                } else {
                    const int gyc = min(max(gy, 0), H - 1);
                    #pragma unroll
                    for (int e = 0; e < 4; ++e) {
                        const int gxe = gx + e;
                        const bool ok = rowok && ((unsigned)gxe < (unsigned)W);
                        const int gxc = min(max(gxe, 0), W - 1);
                        const float t = plane[gyc * W + gxc];
                        sm[bs + e] = ok ? t : 0.0f;
                    }
                }
            }
        }
    }
}

__global__ __launch_bounds__(256) void radon_tile(
    const float* __restrict__ x,       // (B,C,H,W)
    const float* __restrict__ angles,  // (B,K)
    float* __restrict__ out)           // (B,C,H,K)
{
    __shared__ __align__(16) float sm[C * CHS];   // 36864 B -> 4 blocks/CU

    const int bid = blockIdx.x;
    const int th  = bid % NTH;
    const int bk  = bid / NTH;
    const int k   = bk % K;
    const int b   = bk / K;

    const int tid = threadIdx.x;
    const int ww  = tid & 31;          // w within tile
    const int hh  = tid >> 5;          // 0..7; h = h0 + hh + 8*i

    const float theta = angles[b * K + k] * (3.14159265358979323846f / 180.0f);
    float sth, cth;
    sincosf(theta, &sth, &cth);

    const float A  = 0.5f * (W - 1) * (1.0f - cth - sth);
    const float Bc = 0.5f * (H - 1) * (1.0f + sth - cth);

    const int h0 = th * TILE;
    const float hbase = (float)(h0 + hh);
    const float s8 = 8.0f * sth, c8 = 8.0f * cth;

    const float* __restrict__ img = x + (size_t)b * (C * H * W);

    float acc[4][C];
    #pragma unroll
    for (int i = 0; i < 4; ++i)
        #pragma unroll
        for (int c = 0; c < C; ++c) acc[i][c] = 0.0f;

    float4 pf[C][3];
    Cat cur = tile_cat(A, Bc, sth, cth, h0, 0);
    if (cur.stage) issue_loads(img, tid, cur.xal, cur.ym, pf);

    for (int tw = 0; tw < NTW; ++tw) {
        Cat nxt; nxt.stage = 0; nxt.xal = 0; nxt.ym = 0;
        if (tw + 1 < NTW) nxt = tile_cat(A, Bc, sth, cth, h0, tw + 1);

        if (cur.stage) {
            __syncthreads();                       // prior sampling done
            write_stage(img, sm, tid, cur.xal, cur.ym, pf);
        }
        if (nxt.stage) issue_loads(img, tid, nxt.xal, nxt.ym, pf);  // overlap
        if (cur.stage) {
            __syncthreads();                       // LDS tile ready
            const float wf = (float)(tw * TILE + ww);
            float fx = fmaf(hbase, sth, fmaf(wf,  cth, A));
            float fy = fmaf(hbase, cth, fmaf(wf, -sth, Bc));
            #pragma unroll
            for (int i = 0; i < 4; ++i) {
                const float xf = floorf(fx), yf = floorf(fy);
                const int lx = (int)xf - cur.xal;  // [1, 49] < 64
                const int ly = (int)yf - cur.ym;   // [1, 46] < 47
                const float wx1 = fx - xf, wy1 = fy - yf;
                const float wx0 = 1.0f - wx1, wy0 = 1.0f - wy1;
                const float w00 = wy0 * wx0, w01 = wy0 * wx1;
                const float w10 = wy1 * wx0, w11 = wy1 * wx1;
                const int r0 = ly * BBS, r1 = r0 + BBS;
                const int v0 = (ly & 7) << 2;
                const int v1 = ((ly + 1) & 7) << 2;
                const int s00 = r0 + (lx ^ v0);
                const int s01 = r0 + ((lx + 1) ^ v0);
                const int s10 = r1 + (lx ^ v1);
                const int s11 = r1 + ((lx + 1) ^ v1);
                #pragma unroll
                for (int c = 0; c < C; ++c) {
                    const int cb = c * CHS;
                    const float p00 = sm[cb + s00];
                    const float p01 = sm[cb + s01];
                    const float p10 = sm[cb + s10];
                    const float p11 = sm[cb + s11];
                    acc[i][c] = fmaf(w00, p00, fmaf(w01, p01,
                                fmaf(w10, p10, fmaf(w11, p11, acc[i][c]))));
                }
                fx += s8; fy += c8;
            }
        }
        cur = nxt;
    }

    // reduce over the 32 ww-lanes (xor masks <32 stay within the ww group)
    #pragma unroll
    for (int i = 0; i < 4; ++i) {
        #pragma unroll
        for (int c = 0; c < C; ++c) {
            float s = acc[i][c];
            #pragma unroll
            for (int m = 16; m >= 1; m >>= 1) s += __shfl_xor(s, m, 64);
            if (ww == 0) {
                const int h = h0 + hh + 8 * i;
                out[((size_t)(b * C + c) * H + h) * K + k] = s;
            }
        }
    }
}

extern "C" void kernel_launch(void* const* d_in, const int* in_sizes, int n_in,
                              void* d_out, int out_size, void* d_ws, size_t ws_size,
                              hipStream_t stream) {
    const float* x      = (const float*)d_in[0];
    const float* angles = (const float*)d_in[1];
    float* out          = (float*)d_out;

    radon_tile<<<B * K * NTH, 256, 0, stream>>>(x, angles, out);  // 4320 blocks
}

// Round 7
// 235.291 us; speedup vs baseline: 4.0692x; 1.0106x over previous
//
#include <hip/hip_runtime.h>
#include <math.h>

// FastRadonTransform via LDS-staged rotated-tile sampling, v5.
// fx = A + w*cos + h*sin ; fy = Bc - w*sin + h*cos (exact, H==W, align_corners).
// 32x32 (h,w) sample tile -> rigid rotated patch, bbox <= 46x47 px.
// Stage 48x64 float4-aligned window per channel into LDS; in-row swizzle
// slot = r*64 + (col ^ ((r&7)<<2)) (bijective, write-contiguous).
// NEW (v5): angle-adaptive lane mapping. Lanes walk w when |cos|>=|sin|
// (per-lane image step (cos,-sin)) else walk h (step (sin,cos)) -> per-lane
// x-step >= 0.707 at every angle -> LDS reads span >=22 banks (<=2-way, free).
// Mapping A reduces over w with shuffles; mapping B reduces 8 w-groups via LDS.

constexpr int B = 2, C = 3, H = 384, W = 384, K = 180;
constexpr int TILE = 32;
constexpr int NTW  = W / TILE;      // 12
constexpr int NTH  = H / TILE;      // 12
constexpr int ROWS = 48;
constexpr int BBS  = 64;            // row stride (mult of 32 -> bijective swizzle)
constexpr int CHS  = ROWS * BBS;    // 3072 floats per channel

struct Cat { int stage; int xal; int ym; };

__device__ __forceinline__ Cat tile_cat(float A, float Bc, float sth, float cth,
                                        int h0, int tw) {
    const float w0f = (float)(tw * TILE), w1f = w0f + (TILE - 1);
    const float h0f = (float)h0,          h1f = h0f + (TILE - 1);
    const float minfx = A  + fminf(w0f * cth, w1f * cth) + fminf(h0f * sth, h1f * sth);
    const float minfy = Bc + fminf(-w0f * sth, -w1f * sth) + fminf(h0f * cth, h1f * cth);
    Cat c;
    const int xm = (int)floorf(minfx) - 1;
    c.ym  = (int)floorf(minfy) - 1;
    c.xal = xm & ~3;
    const bool skip = (xm + 47 < 0) | (xm > W - 1) | (c.ym + 47 < 0) | (c.ym > H - 1);
    c.stage = skip ? 0 : 1;
    return c;
}

// Staging: u = tid + 256j (j<3), r = u>>4 in [0,48), g = u&15 in [0,16).
__device__ __forceinline__ void issue_loads(const float* __restrict__ img,
                                            int tid, int xal, int ym,
                                            float4 (&pf)[C][3]) {
    #pragma unroll
    for (int c = 0; c < C; ++c) {
        const float* __restrict__ plane = img + c * (H * W);
        #pragma unroll
        for (int j = 0; j < 3; ++j) {
            const int u = tid + 256 * j;
            const int r = u >> 4;
            const int g = u & 15;
            const int gy = min(max(ym + r, 0), H - 1);
            const int gx = min(max(xal + 4 * g, 0), W - 4);  // stays 4-aligned
            pf[c][j] = *reinterpret_cast<const float4*>(plane + gy * W + gx);
        }
    }
}

__device__ __forceinline__ void write_stage(const float* __restrict__ img,
                                            float* __restrict__ sm,
                                            int tid, int xal, int ym,
                                            const float4 (&pf)[C][3]) {
    const bool interior = (ym >= 0) & (ym <= H - ROWS) &
                          (xal >= 0) & (xal <= W - BBS);
    #pragma unroll
    for (int c = 0; c < C; ++c) {
        const float* __restrict__ plane = img + c * (H * W);
        #pragma unroll
        for (int j = 0; j < 3; ++j) {
            const int u = tid + 256 * j;
            const int r = u >> 4;
            const int g = u & 15;
            const int bs = c * CHS + r * BBS + ((4 * g) ^ ((r & 7) << 2));
            const float4 v = pf[c][j];
            if (interior) {
                *reinterpret_cast<float4*>(sm + bs) = v;
            } else {
                const int gy = ym + r;
                const int gx = xal + 4 * g;
                const bool rowok = ((unsigned)gy < (unsigned)H);
                if (rowok && gx >= 0 && gx <= W - 4) {
                    *reinterpret_cast<float4*>(sm + bs) = v;
                } else {
                    const int gyc = min(max(gy, 0), H - 1);
                    #pragma unroll
                    for (int e = 0; e < 4; ++e) {
                        const int gxe = gx + e;
                        const bool ok = rowok && ((unsigned)gxe < (unsigned)W);
                        const int gxc = min(max(gxe, 0), W - 1);
                        const float t = plane[gyc * W + gxc];
                        sm[bs + e] = ok ? t : 0.0f;
                    }
                }
            }
        }
    }
}

__global__ __launch_bounds__(256) void radon_tile(
    const float* __restrict__ x,       // (B,C,H,W)
    const float* __restrict__ angles,  // (B,K)
    float* __restrict__ out)           // (B,C,H,K)
{
    __shared__ __align__(16) float sm[C * CHS];   // 36864 B -> 4 blocks/CU

    const int bid = blockIdx.x;
    const int th  = bid % NTH;
    const int bk  = bid / NTH;
    const int k   = bk % K;
    const int b   = bk / K;

    const int tid = threadIdx.x;
    const int u1  = tid & 31;          // fine lane index (32 values)
    const int u8  = tid >> 5;          // group index (8 values)

    const float theta = angles[b * K + k] * (3.14159265358979323846f / 180.0f);
    float sth, cth;
    sincosf(theta, &sth, &cth);

    const float A  = 0.5f * (W - 1) * (1.0f - cth - sth);
    const float Bc = 0.5f * (H - 1) * (1.0f + sth - cth);

    // mapping select (block-uniform): lanes walk the axis with x-step >= .707
    const bool mapB = fabsf(sth) > fabsf(cth);
    // mapping A: w = w0+u1, h = h0+u8+8i  (i-step = h+8 -> (+8s, +8c))
    // mapping B: h = h0+u1, w = w0+u8+8i  (i-step = w+8 -> (+8c, -8s))
    const int wofs = mapB ? u8 : u1;
    const int hofs = mapB ? u1 : u8;
    const float dix = mapB ? 8.0f * cth :  8.0f * sth;
    const float diy = mapB ? -8.0f * sth : 8.0f * cth;

    const int h0 = th * TILE;
    const float hf = (float)(h0 + hofs);

    const float* __restrict__ img = x + (size_t)b * (C * H * W);

    float acc[4][C];
    #pragma unroll
    for (int i = 0; i < 4; ++i)
        #pragma unroll
        for (int c = 0; c < C; ++c) acc[i][c] = 0.0f;

    float4 pf[C][3];
    Cat cur = tile_cat(A, Bc, sth, cth, h0, 0);
    if (cur.stage) issue_loads(img, tid, cur.xal, cur.ym, pf);

    for (int tw = 0; tw < NTW; ++tw) {
        Cat nxt; nxt.stage = 0; nxt.xal = 0; nxt.ym = 0;
        if (tw + 1 < NTW) nxt = tile_cat(A, Bc, sth, cth, h0, tw + 1);

        if (cur.stage) {
            __syncthreads();                       // prior sampling done
            write_stage(img, sm, tid, cur.xal, cur.ym, pf);
        }
        if (nxt.stage) issue_loads(img, tid, nxt.xal, nxt.ym, pf);  // overlap
        if (cur.stage) {
            __syncthreads();                       // LDS tile ready
            const float wf = (float)(tw * TILE + wofs);
            float fx = fmaf(hf, sth, fmaf(wf,  cth, A));
            float fy = fmaf(hf, cth, fmaf(wf, -sth, Bc));
            #pragma unroll
            for (int i = 0; i < 4; ++i) {
                const float xf = floorf(fx), yf = floorf(fy);
                const int lx = (int)xf - cur.xal;  // [1, 49] < 64
                const int ly = (int)yf - cur.ym;   // [1, 46] < 47
                const float wx1 = fx - xf, wy1 = fy - yf;
                const float wx0 = 1.0f - wx1, wy0 = 1.0f - wy1;
                const float w00 = wy0 * wx0, w01 = wy0 * wx1;
                const float w10 = wy1 * wx0, w11 = wy1 * wx1;
                const int r0 = ly * BBS, r1 = r0 + BBS;
                const int v0 = (ly & 7) << 2;
                const int v1 = ((ly + 1) & 7) << 2;
                const int s00 = r0 + (lx ^ v0);
                const int s01 = r0 + ((lx + 1) ^ v0);
                const int s10 = r1 + (lx ^ v1);
                const int s11 = r1 + ((lx + 1) ^ v1);
                #pragma unroll
                for (int c = 0; c < C; ++c) {
                    const int cb = c * CHS;
                    const float p00 = sm[cb + s00];
                    const float p01 = sm[cb + s01];
                    const float p10 = sm[cb + s10];
                    const float p11 = sm[cb + s11];
                    acc[i][c] = fmaf(w00, p00, fmaf(w01, p01,
                                fmaf(w10, p10, fmaf(w11, p11, acc[i][c]))));
                }
                fx += dix; fy += diy;
            }
        }
        cur = nxt;
    }

    if (!mapB) {
        // reduce over the 32 u1-lanes (w); xor masks <32 stay in each half
        #pragma unroll
        for (int i = 0; i < 4; ++i) {
            #pragma unroll
            for (int c = 0; c < C; ++c) {
                float s = acc[i][c];
                #pragma unroll
                for (int m = 16; m >= 1; m >>= 1) s += __shfl_xor(s, m, 64);
                if (u1 == 0) {
                    const int h = h0 + u8 + 8 * i;
                    out[((size_t)(b * C + c) * H + h) * K + k] = s;
                }
            }
        }
    } else {
        // each thread owns one h = h0+u1; sum its 4 w-chunks, then reduce
        // the 8 u8-groups through LDS (reused; sync before overwrite).
        __syncthreads();
        #pragma unroll
        for (int c = 0; c < C; ++c) {
            const float s = (acc[0][c] + acc[1][c]) + (acc[2][c] + acc[3][c]);
            sm[(c * 8 + u8) * 32 + u1] = s;
        }
        __syncthreads();
        if (tid < C * 32) {
            const int c = tid >> 5;
            const int l = tid & 31;
            float s = 0.0f;
            #pragma unroll
            for (int g = 0; g < 8; ++g) s += sm[(c * 8 + g) * 32 + l];
            out[((size_t)(b * C + c) * H + (h0 + l)) * K + k] = s;
        }
    }
}

extern "C" void kernel_launch(void* const* d_in, const int* in_sizes, int n_in,
                              void* d_out, int out_size, void* d_ws, size_t ws_size,
                              hipStream_t stream) {
    const float* x      = (const float*)d_in[0];
    const float* angles = (const float*)d_in[1];
    float* out          = (float*)d_out;

    radon_tile<<<B * K * NTH, 256, 0, stream>>>(x, angles, out);  // 4320 blocks
}

// Round 8
// 215.652 us; speedup vs baseline: 4.4397x; 1.0911x over previous
//
#include <hip/hip_runtime.h>
#include <math.h>

// FastRadonTransform via LDS-staged rotated-tile sampling, v6.
// fx = A + w*cos + h*sin ; fy = Bc - w*sin + h*cos (exact, H==W, align_corners).
// Stage 48row x 64col (+4 pad) window per channel; slot = ly*68 + (lx ^ v),
// v = (ly&7)<<2. Bank = (4*ly + (lx^v)) mod 32: ly enters additively (stride
// 68 = 4 mod 32) AND via XOR -> no stable resonance at any angle (v4/v5's
// BBS=64 made bank bits 0-1 pure lx -> mid-band 3-way clustering, 3.5e7
// conflict-cycles that were layout-invariant across 3 prior layouts).
// Angle-adaptive lane mapping kept: lanes walk w when |cos|>=|sin| else h.
// Per-tile seeds fold in (xal,ym) so sampling needs no int subtracts.

constexpr int B = 2, C = 3, H = 384, W = 384, K = 180;
constexpr int TILE = 32;
constexpr int NTW  = W / TILE;      // 12
constexpr int NTH  = H / TILE;      // 12
constexpr int ROWS = 48;
constexpr int BBS  = 68;            // 64 data cols + 4 pad; 68 mod 32 = 4
constexpr int CHS  = ROWS * BBS;    // 3264 floats per channel

struct Cat { int stage; int xal; int ym; };

__device__ __forceinline__ Cat tile_cat(float A, float Bc, float sth, float cth,
                                        int h0, int tw) {
    const float w0f = (float)(tw * TILE), w1f = w0f + (TILE - 1);
    const float h0f = (float)h0,          h1f = h0f + (TILE - 1);
    const float minfx = A  + fminf(w0f * cth, w1f * cth) + fminf(h0f * sth, h1f * sth);
    const float minfy = Bc + fminf(-w0f * sth, -w1f * sth) + fminf(h0f * cth, h1f * cth);
    Cat c;
    const int xm = (int)floorf(minfx) - 1;
    c.ym  = (int)floorf(minfy) - 1;
    c.xal = xm & ~3;
    const bool skip = (xm + 47 < 0) | (xm > W - 1) | (c.ym + 47 < 0) | (c.ym > H - 1);
    c.stage = skip ? 0 : 1;
    return c;
}

// Staging: u = tid + 256j (j<3), r = u>>4 in [0,48), g = u&15 in [0,16).
__device__ __forceinline__ void issue_loads(const float* __restrict__ img,
                                            int tid, int xal, int ym,
                                            float4 (&pf)[C][3]) {
    #pragma unroll
    for (int c = 0; c < C; ++c) {
        const float* __restrict__ plane = img + c * (H * W);
        #pragma unroll
        for (int j = 0; j < 3; ++j) {
            const int u = tid + 256 * j;
            const int r = u >> 4;
            const int g = u & 15;
            const int gy = min(max(ym + r, 0), H - 1);
            const int gx = min(max(xal + 4 * g, 0), W - 4);  // stays 4-aligned
            pf[c][j] = *reinterpret_cast<const float4*>(plane + gy * W + gx);
        }
    }
}

__device__ __forceinline__ void write_stage(const float* __restrict__ img,
                                            float* __restrict__ sm,
                                            int tid, int xal, int ym,
                                            const float4 (&pf)[C][3]) {
    const bool interior = (ym >= 0) & (ym <= H - ROWS) &
                          (xal >= 0) & (xal <= W - 64);
    #pragma unroll
    for (int c = 0; c < C; ++c) {
        const float* __restrict__ plane = img + c * (H * W);
        #pragma unroll
        for (int j = 0; j < 3; ++j) {
            const int u = tid + 256 * j;
            const int r = u >> 4;
            const int g = u & 15;
            // in-row swizzle on the 64-float data region (cols 64-67 = pad)
            const int bs = c * CHS + r * BBS + ((4 * g) ^ ((r & 7) << 2));
            const float4 v = pf[c][j];
            if (interior) {
                *reinterpret_cast<float4*>(sm + bs) = v;
            } else {
                const int gy = ym + r;
                const int gx = xal + 4 * g;
                const bool rowok = ((unsigned)gy < (unsigned)H);
                if (rowok && gx >= 0 && gx <= W - 4) {
                    *reinterpret_cast<float4*>(sm + bs) = v;
                } else {
                    const int gyc = min(max(gy, 0), H - 1);
                    #pragma unroll
                    for (int e = 0; e < 4; ++e) {
                        const int gxe = gx + e;
                        const bool ok = rowok && ((unsigned)gxe < (unsigned)W);
                        const int gxc = min(max(gxe, 0), W - 1);
                        const float t = plane[gyc * W + gxc];
                        sm[bs + e] = ok ? t : 0.0f;
                    }
                }
            }
        }
    }
}

__global__ __launch_bounds__(256) void radon_tile(
    const float* __restrict__ x,       // (B,C,H,W)
    const float* __restrict__ angles,  // (B,K)
    float* __restrict__ out)           // (B,C,H,K)
{
    __shared__ __align__(16) float sm[C * CHS];   // 39168 B -> 4 blocks/CU

    const int bid = blockIdx.x;
    const int th  = bid % NTH;
    const int bk  = bid / NTH;
    const int k   = bk % K;
    const int b   = bk / K;

    const int tid = threadIdx.x;
    const int u1  = tid & 31;          // fine lane index (32 values)
    const int u8  = tid >> 5;          // group index (8 values)

    const float theta = angles[b * K + k] * (3.14159265358979323846f / 180.0f);
    float sth, cth;
    sincosf(theta, &sth, &cth);

    const float A  = 0.5f * (W - 1) * (1.0f - cth - sth);
    const float Bc = 0.5f * (H - 1) * (1.0f + sth - cth);

    // mapping select (block-uniform): lanes walk the axis with x-step >= .707
    const bool mapB = fabsf(sth) > fabsf(cth);
    const int wofs = mapB ? u8 : u1;
    const int hofs = mapB ? u1 : u8;
    const float dix = mapB ? 8.0f * cth :  8.0f * sth;
    const float diy = mapB ? -8.0f * sth : 8.0f * cth;

    const int h0 = th * TILE;
    const float hf = (float)(h0 + hofs);

    const float* __restrict__ img = x + (size_t)b * (C * H * W);

    float acc[4][C];
    #pragma unroll
    for (int i = 0; i < 4; ++i)
        #pragma unroll
        for (int c = 0; c < C; ++c) acc[i][c] = 0.0f;

    float4 pf[C][3];
    Cat cur = tile_cat(A, Bc, sth, cth, h0, 0);
    if (cur.stage) issue_loads(img, tid, cur.xal, cur.ym, pf);

    for (int tw = 0; tw < NTW; ++tw) {
        Cat nxt; nxt.stage = 0; nxt.xal = 0; nxt.ym = 0;
        if (tw + 1 < NTW) nxt = tile_cat(A, Bc, sth, cth, h0, tw + 1);

        if (cur.stage) {
            __syncthreads();                       // prior sampling done
            write_stage(img, sm, tid, cur.xal, cur.ym, pf);
        }
        if (nxt.stage) issue_loads(img, tid, nxt.xal, nxt.ym, pf);  // overlap
        if (cur.stage) {
            __syncthreads();                       // LDS tile ready
            // window-local seeds: fold (xal, ym) in -> lx/ly come straight
            // from floorf, no int subtracts in the loop
            const float wf = (float)(tw * TILE + wofs);
            float fx = fmaf(hf, sth, fmaf(wf,  cth, A)) - (float)cur.xal;
            float fy = fmaf(hf, cth, fmaf(wf, -sth, Bc)) - (float)cur.ym;
            #pragma unroll
            for (int i = 0; i < 4; ++i) {
                const float xf = floorf(fx), yf = floorf(fy);
                const int lx = (int)xf;            // [1, 52] < 64
                const int ly = (int)yf;            // [1, 46] < 48
                const float wx1 = fx - xf, wy1 = fy - yf;
                const float wx0 = 1.0f - wx1, wy0 = 1.0f - wy1;
                const float w00 = wy0 * wx0, w01 = wy0 * wx1;
                const float w10 = wy1 * wx0, w11 = wy1 * wx1;
                const int r0 = ly * BBS, r1 = r0 + BBS;
                const int v0 = (ly & 7) << 2;
                const int v1 = ((ly + 1) & 7) << 2;
                const int s00 = r0 + (lx ^ v0);
                const int s01 = r0 + ((lx + 1) ^ v0);
                const int s10 = r1 + (lx ^ v1);
                const int s11 = r1 + ((lx + 1) ^ v1);
                #pragma unroll
                for (int c = 0; c < C; ++c) {
                    const int cb = c * CHS;
                    const float p00 = sm[cb + s00];
                    const float p01 = sm[cb + s01];
                    const float p10 = sm[cb + s10];
                    const float p11 = sm[cb + s11];
                    acc[i][c] = fmaf(w00, p00, fmaf(w01, p01,
                                fmaf(w10, p10, fmaf(w11, p11, acc[i][c]))));
                }
                fx += dix; fy += diy;
            }
        }
        cur = nxt;
    }

    if (!mapB) {
        // reduce over the 32 u1-lanes (w); xor masks <32 stay in each half
        #pragma unroll
        for (int i = 0; i < 4; ++i) {
            #pragma unroll
            for (int c = 0; c < C; ++c) {
                float s = acc[i][c];
                #pragma unroll
                for (int m = 16; m >= 1; m >>= 1) s += __shfl_xor(s, m, 64);
                if (u1 == 0) {
                    const int h = h0 + u8 + 8 * i;
                    out[((size_t)(b * C + c) * H + h) * K + k] = s;
                }
            }
        }
    } else {
        // each thread owns one h = h0+u1; sum its 4 w-chunks, then reduce
        // the 8 u8-groups through LDS (reused; sync before overwrite).
        __syncthreads();
        #pragma unroll
        for (int c = 0; c < C; ++c) {
            const float s = (acc[0][c] + acc[1][c]) + (acc[2][c] + acc[3][c]);
            sm[(c * 8 + u8) * 32 + u1] = s;
        }
        __syncthreads();
        if (tid < C * 32) {
            const int c = tid >> 5;
            const int l = tid & 31;
            float s = 0.0f;
            #pragma unroll
            for (int g = 0; g < 8; ++g) s += sm[(c * 8 + g) * 32 + l];
            out[((size_t)(b * C + c) * H + (h0 + l)) * K + k] = s;
        }
    }
}

extern "C" void kernel_launch(void* const* d_in, const int* in_sizes, int n_in,
                              void* d_out, int out_size, void* d_ws, size_t ws_size,
                              hipStream_t stream) {
    const float* x      = (const float*)d_in[0];
    const float* angles = (const float*)d_in[1];
    float* out          = (float*)d_out;

    radon_tile<<<B * K * NTH, 256, 0, stream>>>(x, angles, out);  // 4320 blocks
}